// Round 4
// baseline (493.393 us; speedup 1.0000x reference)
//
#include <hip/hip_runtime.h>
#include <stdint.h>

typedef int   int32x4   __attribute__((ext_vector_type(4)));
typedef int   int32x16  __attribute__((ext_vector_type(16)));
typedef float floatx4   __attribute__((ext_vector_type(4)));

#define B_ROWS 131072
#define DK 512           // K (= D)
#define FN 512           // N (= F)
#define BM 64            // rows per tile
#define NBLK 512         // 2 blocks/CU
#define TILES 4          // B_ROWS / BM / NBLK
#define A_SCALE_F ((float)(127.0 / 6.0))

// ---------------- prepass: quantize weights into B-fragment layout -------------
__global__ void wq_quant_kernel(const float* __restrict__ kern,  // [DK][FN]
                                int8_t* __restrict__ wq,         // [FN][DK]
                                float* __restrict__ invcs) {     // [FN]
  __shared__ float smax[256];
  __shared__ float sscale[16];
  const int c = threadIdx.x & 15;
  const int g = threadIdx.x >> 4;
  const int col = blockIdx.x * 16 + c;

  float m = 0.f;
#pragma unroll 8
  for (int i = 0; i < 32; ++i) {
    m = fmaxf(m, fabsf(kern[(size_t)(g * 32 + i) * FN + col]));
  }
  smax[threadIdx.x] = m;
  __syncthreads();
  if (threadIdx.x < 16) {
    float mm = smax[threadIdx.x];
#pragma unroll
    for (int g2 = 1; g2 < 16; ++g2) mm = fmaxf(mm, smax[g2 * 16 + threadIdx.x]);
    const float wb = fmaxf(mm, 1e-6f);
    const float ws = 127.f / wb;               // f32 divide, matches jnp w_scale
    sscale[threadIdx.x] = ws;
    invcs[blockIdx.x * 16 + threadIdx.x] =
        (float)(1.0 / ((double)A_SCALE_F * (double)ws));
  }
  __syncthreads();
  const float ws = sscale[c];
  uint32_t* wq32 = (uint32_t*)(wq + (size_t)col * DK);
#pragma unroll
  for (int d4 = 0; d4 < 8; ++d4) {
    uint32_t p = 0;
#pragma unroll
    for (int j = 0; j < 4; ++j) {
      float v = kern[(size_t)(g * 32 + d4 * 4 + j) * FN + col] * ws;
      v = floorf(v + 0.5f);                    // AQT round: floor(v+0.5)
      v = fminf(fmaxf(v, -127.f), 127.f);
      p |= ((uint32_t)((int)v & 255)) << (8 * j);
    }
    wq32[g * 8 + d4] = p;
  }
}

// ---------------- main GEMM: pipelined over 4 M-tiles, double-buffered LDS -----
// 512 blocks x 512 threads (8 waves: 2M x 4N). Wave = 32 rows x 128 cols via
// mfma_i32_32x32x32_i8, computed as 2 panels of 64 cols (acc 32 regs each).
__global__ __launch_bounds__(512, 4)
void aqt_gemm_kernel(const float* __restrict__ x,     // [B_ROWS][DK]
                     const int8_t* __restrict__ wq,   // [FN][DK]
                     const float* __restrict__ invcs, // [FN]
                     const float* __restrict__ bias,  // [FN]
                     float* __restrict__ out) {       // [B_ROWS][FN]
  __shared__ __align__(16) char xq[2][BM * DK];       // 2 x 32 KB

  const int tid  = threadIdx.x;
  const int lane = tid & 63;
  const int wv   = tid >> 6;        // 0..7
  const int wM   = wv >> 2;         // 0..1 -> 32-row strip
  const int wN   = wv & 3;          // 0..3 -> 128-col strip
  const int l31  = lane & 31;
  const int l5   = lane >> 5;       // k-half

  const int c4 = tid & 127;         // float4 index within a row
  const int r0 = tid >> 7;          // 0..3

  const int arow = wM * 32 + l31;   // A-fragment row within tile
  const int aSwz = (arow & 31) << 4;

  // hoisted per-column dequant constants (4 col-fragments per wave)
  float invc[4], bv[4];
#pragma unroll
  for (int q = 0; q < 4; ++q) {
    const int col = wN * 128 + q * 32 + l31;
    invc[q] = invcs[col];
    bv[q]   = bias[col];
  }
  // hoisted B base pointers
  const int8_t* wqc[4];
#pragma unroll
  for (int q = 0; q < 4; ++q)
    wqc[q] = wq + (size_t)(wN * 128 + q * 32 + l31) * DK;

  const size_t tb0 = (size_t)blockIdx.x * TILES;

  // ---- prologue: stage tile 0 into buffer 0 ----
  {
    const float* xg = x + tb0 * BM * DK;
#pragma unroll
    for (int ch = 0; ch < 2; ++ch) {
      floatx4 v[8];
#pragma unroll
      for (int i = 0; i < 8; ++i) {
        const int r = ch * 32 + i * 4 + r0;
        v[i] = *(const floatx4*)(xg + (size_t)r * DK + c4 * 4);
      }
#pragma unroll
      for (int i = 0; i < 8; ++i) {
        const int r = ch * 32 + i * 4 + r0;
        uint32_t p = 0;
#pragma unroll
        for (int j = 0; j < 4; ++j) {
          float qf = floorf(v[i][j] * A_SCALE_F + 0.5f);   // AQT round
          qf = fminf(fmaxf(qf, -127.f), 127.f);
          p |= ((uint32_t)((int)qf & 255)) << (8 * j);
        }
        *(uint32_t*)(&xq[0][r * DK + ((c4 * 4) ^ ((r & 31) << 4))]) = p;
      }
    }
  }
  __syncthreads();

  for (int t = 0; t < TILES; ++t) {
    const int cur = t & 1;
    const int nxt = cur ^ 1;
    const size_t mBase = (tb0 + t) * BM;
    const float* xgn = x + (tb0 + t + 1) * BM * DK;   // next tile (guarded)
    const bool pf = (t + 1 < TILES);
    const char* bufC = &xq[cur][0];
    char* bufN = &xq[nxt][0];

    // ---- issue chunk-A global loads for tile t+1 (latency hides under panel 0)
    floatx4 va[8];
    if (pf) {
#pragma unroll
      for (int i = 0; i < 8; ++i) {
        const int r = i * 4 + r0;
        va[i] = *(const floatx4*)(xgn + (size_t)r * DK + c4 * 4);
      }
    }

    // ---- panel 0: cols [wN*128, wN*128+64) ----
    int32x16 acc0[2];
    acc0[0] = (int32x16)(0);
    acc0[1] = (int32x16)(0);
#pragma unroll
    for (int ks = 0; ks < 16; ++ks) {
      const int kb = ks * 32 + l5 * 16;
      int32x4 a  = *(const int32x4*)(bufC + arow * DK + (kb ^ aSwz));
      int32x4 b0 = *(const int32x4*)(wqc[0] + kb);
      int32x4 b1 = *(const int32x4*)(wqc[1] + kb);
      acc0[0] = __builtin_amdgcn_mfma_i32_32x32x32_i8(a, b0, acc0[0], 0, 0, 0);
      acc0[1] = __builtin_amdgcn_mfma_i32_32x32x32_i8(a, b1, acc0[1], 0, 0, 0);
    }

    // ---- quantize chunk A into other buffer; issue chunk-B loads ----
    floatx4 vb[8];
    if (pf) {
#pragma unroll
      for (int i = 0; i < 8; ++i) {
        const int r = i * 4 + r0;
        uint32_t p = 0;
#pragma unroll
        for (int j = 0; j < 4; ++j) {
          float qf = floorf(va[i][j] * A_SCALE_F + 0.5f);
          qf = fminf(fmaxf(qf, -127.f), 127.f);
          p |= ((uint32_t)((int)qf & 255)) << (8 * j);
        }
        *(uint32_t*)(&bufN[r * DK + ((c4 * 4) ^ ((r & 31) << 4))]) = p;
      }
#pragma unroll
      for (int i = 0; i < 8; ++i) {
        const int r = 32 + i * 4 + r0;
        vb[i] = *(const floatx4*)(xgn + (size_t)r * DK + c4 * 4);
      }
    }

    // ---- epilogue panel 0 (frees acc0 before panel 1) ----
#pragma unroll
    for (int n = 0; n < 2; ++n) {
      const int col = wN * 128 + n * 32 + l31;
#pragma unroll
      for (int r = 0; r < 16; ++r) {
        const int rowl = (r & 3) + 8 * (r >> 2) + 4 * l5;
        const size_t row = mBase + (size_t)(wM * 32 + rowl);
        out[row * FN + col] = (float)acc0[n][r] * invc[n] + bv[n];
      }
    }

    // ---- panel 1: cols [wN*128+64, wN*128+128) ----
    int32x16 acc1[2];
    acc1[0] = (int32x16)(0);
    acc1[1] = (int32x16)(0);
#pragma unroll
    for (int ks = 0; ks < 16; ++ks) {
      const int kb = ks * 32 + l5 * 16;
      int32x4 a  = *(const int32x4*)(bufC + arow * DK + (kb ^ aSwz));
      int32x4 b2 = *(const int32x4*)(wqc[2] + kb);
      int32x4 b3 = *(const int32x4*)(wqc[3] + kb);
      acc1[0] = __builtin_amdgcn_mfma_i32_32x32x32_i8(a, b2, acc1[0], 0, 0, 0);
      acc1[1] = __builtin_amdgcn_mfma_i32_32x32x32_i8(a, b3, acc1[1], 0, 0, 0);
    }

    // ---- quantize chunk B into other buffer ----
    if (pf) {
#pragma unroll
      for (int i = 0; i < 8; ++i) {
        const int r = 32 + i * 4 + r0;
        uint32_t p = 0;
#pragma unroll
        for (int j = 0; j < 4; ++j) {
          float qf = floorf(vb[i][j] * A_SCALE_F + 0.5f);
          qf = fminf(fmaxf(qf, -127.f), 127.f);
          p |= ((uint32_t)((int)qf & 255)) << (8 * j);
        }
        *(uint32_t*)(&bufN[r * DK + ((c4 * 4) ^ ((r & 31) << 4))]) = p;
      }
    }

    // ---- epilogue panel 1 ----
#pragma unroll
    for (int n = 0; n < 2; ++n) {
      const int col = wN * 128 + 64 + n * 32 + l31;
#pragma unroll
      for (int r = 0; r < 16; ++r) {
        const int rowl = (r & 3) + 8 * (r >> 2) + 4 * l5;
        const size_t row = mBase + (size_t)(wM * 32 + rowl);
        out[row * FN + col] = (float)acc1[n][r] * invc[2 + n] + bv[2 + n];
      }
    }

    __syncthreads();   // nxt writes done; cur free for overwrite next iter
  }
}

extern "C" void kernel_launch(void* const* d_in, const int* in_sizes, int n_in,
                              void* d_out, int out_size, void* d_ws, size_t ws_size,
                              hipStream_t stream) {
  const float* x    = (const float*)d_in[0];
  const float* kern = (const float*)d_in[1];
  const float* bias = (const float*)d_in[2];
  // d_in[3] = padding_mask: fixed act bounds + eval mode -> not in the math.

  int8_t* wq    = (int8_t*)d_ws;                           // 256 KB
  float*  invcs = (float*)((char*)d_ws + (size_t)FN * DK); // 2 KB

  wq_quant_kernel<<<32, 256, 0, stream>>>(kern, wq, invcs);
  aqt_gemm_kernel<<<NBLK, 512, 0, stream>>>(x, wq, invcs, bias, (float*)d_out);
}

// Round 5
// 174.180 us; speedup vs baseline: 2.8327x; 2.8327x over previous
//
#include <hip/hip_runtime.h>
#include <stdint.h>

typedef int   int32x4   __attribute__((ext_vector_type(4)));
typedef int   int32x16  __attribute__((ext_vector_type(16)));
typedef float floatx4   __attribute__((ext_vector_type(4)));

#define B_ROWS 131072
#define DK 512           // K (= D)
#define FN 512           // N (= F)
#define A_SCALE_F ((float)(127.0 / 6.0))

// split-GEMM geometry
#define GBLK 256         // 1 block/CU
#define GT   1024        // threads (16 waves; wave w owns cols [w*32, w*32+32))
#define BMS  32          // rows per tile
#define GTILES (B_ROWS / BMS / GBLK)   // 16

// ---------------- prepass: quantize weights into B-fragment layout -------------
__global__ void wq_quant_kernel(const float* __restrict__ kern,  // [DK][FN]
                                int8_t* __restrict__ wq,         // [FN][DK]
                                float* __restrict__ invcs) {     // [FN]
  __shared__ float smax[256];
  __shared__ float sscale[16];
  const int c = threadIdx.x & 15;
  const int g = threadIdx.x >> 4;
  const int col = blockIdx.x * 16 + c;

  float m = 0.f;
#pragma unroll 8
  for (int i = 0; i < 32; ++i) {
    m = fmaxf(m, fabsf(kern[(size_t)(g * 32 + i) * FN + col]));
  }
  smax[threadIdx.x] = m;
  __syncthreads();
  if (threadIdx.x < 16) {
    float mm = smax[threadIdx.x];
#pragma unroll
    for (int g2 = 1; g2 < 16; ++g2) mm = fmaxf(mm, smax[g2 * 16 + threadIdx.x]);
    const float wb = fmaxf(mm, 1e-6f);
    const float ws = 127.f / wb;               // f32 divide, matches jnp w_scale
    sscale[threadIdx.x] = ws;
    invcs[blockIdx.x * 16 + threadIdx.x] =
        (float)(1.0 / ((double)A_SCALE_F * (double)ws));
  }
  __syncthreads();
  const float ws = sscale[c];
  uint32_t* wq32 = (uint32_t*)(wq + (size_t)col * DK);
#pragma unroll
  for (int d4 = 0; d4 < 8; ++d4) {
    uint32_t p = 0;
#pragma unroll
    for (int j = 0; j < 4; ++j) {
      float v = kern[(size_t)(g * 32 + d4 * 4 + j) * FN + col] * ws;
      v = floorf(v + 0.5f);                    // AQT round: floor(v+0.5)
      v = fminf(fmaxf(v, -127.f), 127.f);
      p |= ((uint32_t)((int)v & 255)) << (8 * j);
    }
    wq32[g * 8 + d4] = p;
  }
}

// ---------------- x quantize: streaming f32 -> int8, PRE-SWIZZLED layout -------
// xq8[row*512 + ((4*c4) ^ ((row&31)<<4)) .. +3] = int8(round(x[row][4c4..4c4+3]*s))
// Pre-swizzling lets the GEMM stage with linear global_load_lds and read LDS
// with the XOR pattern (conflict-free, measured 0 in R3).
__global__ __launch_bounds__(256)
void xquant_kernel(const float* __restrict__ x, uint8_t* __restrict__ xq8) {
  const int T = 2048 * 256;                    // total threads
  const int G = B_ROWS * (DK / 4);             // float4 granules (multiple of 4T)
  for (int g = blockIdx.x * 256 + threadIdx.x; g < G; g += 4 * T) {
    floatx4 v[4];
#pragma unroll
    for (int u = 0; u < 4; ++u)
      v[u] = *(const floatx4*)(x + (size_t)(g + u * T) * 4);
#pragma unroll
    for (int u = 0; u < 4; ++u) {
      const int gg = g + u * T;
      const int row = gg >> 7;
      const int c4  = gg & 127;
      uint32_t p = 0;
#pragma unroll
      for (int j = 0; j < 4; ++j) {
        float q = floorf(v[u][j] * A_SCALE_F + 0.5f);   // AQT round
        q = fminf(fmaxf(q, -127.f), 127.f);
        p |= ((uint32_t)((int)q & 255)) << (8 * j);
      }
      *(uint32_t*)(xq8 + (size_t)row * DK + ((c4 * 4) ^ ((row & 31) << 4))) = p;
    }
  }
}

// ---------------- main GEMM (split path) ---------------------------------------
// 256 blocks x 1024 threads (16 waves). Wave w: cols [w*32, w*32+32), all K.
// B held ENTIRELY in registers (64 VGPR) -> K-loop has zero global loads.
// A staged tile-by-tile via fire-and-forget global_load_lds (1 instr/thread),
// double-buffered; counted vmcnt(16) lets epilogue stores drain in background.
__global__ __launch_bounds__(GT, 4)
void aqt_gemm_split(const uint8_t* __restrict__ xq8,  // [B_ROWS][DK] pre-swizzled
                    const int8_t* __restrict__ wq,    // [FN][DK]
                    const float* __restrict__ invcs,  // [FN]
                    const float* __restrict__ bias,   // [FN]
                    float* __restrict__ out) {        // [B_ROWS][FN]
  __shared__ __align__(16) uint8_t xq[2][BMS * DK];   // 2 x 16 KB

  const int tid  = threadIdx.x;
  const int lane = tid & 63;
  const int wv   = tid >> 6;       // 0..15
  const int l31  = lane & 31;
  const int l5   = lane >> 5;

  // ---- B fragments into registers, once (L2-hot after first blocks) ----
  const int col = wv * 32 + l31;
  int32x4 Bf[16];
#pragma unroll
  for (int ks = 0; ks < 16; ++ks)
    Bf[ks] = *(const int32x4*)(wq + (size_t)col * DK + ks * 32 + l5 * 16);
  const float inv = invcs[col];
  const float bv  = bias[col];

  const size_t row0 = (size_t)blockIdx.x * (GTILES * BMS);

  // ---- prologue: stage tile 0 ----
  {
    const uint8_t* src = xq8 + row0 * DK + wv * 1024 + lane * 16;
    __builtin_amdgcn_global_load_lds(
        (const __attribute__((address_space(1))) uint32_t*)src,
        (__attribute__((address_space(3))) uint32_t*)&xq[0][wv * 1024],
        16, 0, 0);
  }
  asm volatile("s_waitcnt vmcnt(0)" ::: "memory");
  __builtin_amdgcn_s_barrier();

  for (int t = 0; t < GTILES; ++t) {
    uint8_t* bufC = &xq[t & 1][0];
    uint8_t* bufN = &xq[(t & 1) ^ 1][0];
    const size_t rowT = row0 + (size_t)t * BMS;

    // issue next tile's stage (fire-and-forget; completes during K-loop)
    if (t + 1 < GTILES) {
      const uint8_t* src = xq8 + (rowT + BMS) * DK + wv * 1024 + lane * 16;
      __builtin_amdgcn_global_load_lds(
          (const __attribute__((address_space(1))) uint32_t*)src,
          (__attribute__((address_space(3))) uint32_t*)&bufN[wv * 1024],
          16, 0, 0);
    }

    // K-loop: LDS A + in-register B only
    int32x16 acc = (int32x16)(0);
    const uint8_t* aRow = bufC + l31 * DK;
    const int aswz = l31 << 4;
#pragma unroll
    for (int ks = 0; ks < 16; ++ks) {
      int32x4 a = *(const int32x4*)(aRow + ((ks * 32 + l5 * 16) ^ aswz));
      acc = __builtin_amdgcn_mfma_i32_32x32x32_i8(a, Bf[ks], acc, 0, 0, 0);
    }

    // epilogue: 16 stores, full 128B segments (R3-validated layout)
#pragma unroll
    for (int r = 0; r < 16; ++r) {
      const int rowl = (r & 3) + 8 * (r >> 2) + 4 * l5;
      out[(rowT + rowl) * FN + col] = (float)acc[r] * inv + bv;
    }

    // counted wait: 1 gll + 16 stores outstanding -> <=16 means gll landed;
    // stores keep draining across the next K-loop. Raw barrier (no vmcnt(0)).
    asm volatile("s_waitcnt vmcnt(16)" ::: "memory");
    __builtin_amdgcn_s_barrier();
  }
}

// ---------------- fallback fused GEMM (R3, needs only 264 KB ws) ---------------
#define BMF 64
__global__ __launch_bounds__(512, 4)
void aqt_gemm_fused(const float* __restrict__ x, const int8_t* __restrict__ wq,
                    const float* __restrict__ invcs, const float* __restrict__ bias,
                    float* __restrict__ out) {
  __shared__ __align__(16) char xq[BMF * DK];

  const int tid  = threadIdx.x;
  const int lane = tid & 63;
  const int wv   = tid >> 6;
  const int wM   = wv >> 2;
  const int wN   = wv & 3;
  const int l31  = lane & 31;
  const int l5   = lane >> 5;

  const size_t mBase = (size_t)blockIdx.x * BMF;
  const float* xg = x + mBase * DK;

  {
    const int c4 = tid & 127;
    const int r0 = tid >> 7;
    floatx4 v[16];
#pragma unroll
    for (int i = 0; i < 16; ++i)
      v[i] = *(const floatx4*)(xg + (size_t)(i * 4 + r0) * DK + c4 * 4);
#pragma unroll
    for (int i = 0; i < 16; ++i) {
      const int r = i * 4 + r0;
      uint32_t p = 0;
#pragma unroll
      for (int j = 0; j < 4; ++j) {
        float q = floorf(v[i][j] * A_SCALE_F + 0.5f);
        q = fminf(fmaxf(q, -127.f), 127.f);
        p |= ((uint32_t)((int)q & 255)) << (8 * j);
      }
      *(uint32_t*)(&xq[r * DK + ((c4 * 4) ^ ((r & 31) << 4))]) = p;
    }
  }
  __syncthreads();

  int32x16 acc[4];
#pragma unroll
  for (int n = 0; n < 4; ++n) acc[n] = (int32x16)(0);

  const int arow = wM * 32 + l31;
  const char* aBase = &xq[arow * DK];
  const int aSwz = (arow & 31) << 4;

#pragma unroll
  for (int ks = 0; ks < 16; ++ks) {
    const int kb = ks * 32 + l5 * 16;
    int32x4 a = *(const int32x4*)(aBase + (kb ^ aSwz));
    int32x4 b[4];
#pragma unroll
    for (int n = 0; n < 4; ++n)
      b[n] = *(const int32x4*)(wq + (size_t)(wN * 128 + n * 32 + l31) * DK + kb);
#pragma unroll
    for (int n = 0; n < 4; ++n)
      acc[n] = __builtin_amdgcn_mfma_i32_32x32x32_i8(a, b[n], acc[n], 0, 0, 0);
  }

#pragma unroll
  for (int n = 0; n < 4; ++n) {
    const int ccol = wN * 128 + n * 32 + l31;
    const float cinv = invcs[ccol];
    const float cbv  = bias[ccol];
#pragma unroll
    for (int r = 0; r < 16; ++r) {
      const int rowl = (r & 3) + 8 * (r >> 2) + 4 * l5;
      out[(mBase + wM * 32 + rowl) * FN + ccol] = (float)acc[n][r] * cinv + cbv;
    }
  }
}

extern "C" void kernel_launch(void* const* d_in, const int* in_sizes, int n_in,
                              void* d_out, int out_size, void* d_ws, size_t ws_size,
                              hipStream_t stream) {
  const float* x    = (const float*)d_in[0];
  const float* kern = (const float*)d_in[1];
  const float* bias = (const float*)d_in[2];
  // d_in[3] = padding_mask: fixed act bounds + eval mode -> not in the math.

  int8_t* wq    = (int8_t*)d_ws;                            // 256 KB
  float*  invcs = (float*)((char*)d_ws + (size_t)FN * DK);  // 2 KB

  wq_quant_kernel<<<32, 256, 0, stream>>>(kern, wq, invcs);

  const size_t xq8_off  = (size_t)FN * DK + 4096;
  const size_t ws_need  = xq8_off + (size_t)B_ROWS * DK;
  if (ws_size >= ws_need) {
    uint8_t* xq8 = (uint8_t*)d_ws + xq8_off;                // 64 MB
    xquant_kernel<<<2048, 256, 0, stream>>>(x, xq8);
    aqt_gemm_split<<<GBLK, GT, 0, stream>>>(xq8, wq, invcs, bias, (float*)d_out);
  } else {
    aqt_gemm_fused<<<B_ROWS / BMF, 512, 0, stream>>>(x, wq, invcs, bias, (float*)d_out);
  }
}

// Round 6
// 131.857 us; speedup vs baseline: 3.7419x; 1.3210x over previous
//
#include <hip/hip_runtime.h>
#include <stdint.h>

typedef int   int32x4   __attribute__((ext_vector_type(4)));
typedef int   int32x16  __attribute__((ext_vector_type(16)));
typedef float floatx4   __attribute__((ext_vector_type(4)));

#define B_ROWS 131072
#define DK 512           // K (= D)
#define FN 512           // N (= F)
#define A_SCALE_F ((float)(127.0 / 6.0))

// fused-GEMM geometry: 256 blocks x 1024 threads (16 waves), persistent.
// Wave w owns cols [w*32, w*32+32) x full K; B lives in 64 VGPRs.
#define GBLK 256
#define GT   1024
#define BMS  32
#define GTILES (B_ROWS / BMS / GBLK)   // 16

// ---------------- prepass: quantize weights into B-fragment layout -------------
// 128 blocks x 256 threads; block = 4 cols, 64 row-groups of 8 rows.
__global__ void wq_quant_kernel(const float* __restrict__ kern,  // [DK][FN]
                                int8_t* __restrict__ wq,         // [FN][DK]
                                float* __restrict__ invcs) {     // [FN]
  __shared__ float smax[256];
  __shared__ float sscale[4];
  const int c = threadIdx.x & 3;         // col within block
  const int g = threadIdx.x >> 2;        // row-group 0..63 (8 rows each)
  const int col = blockIdx.x * 4 + c;

  float m = 0.f;
#pragma unroll
  for (int i = 0; i < 8; ++i) {
    m = fmaxf(m, fabsf(kern[(size_t)(g * 8 + i) * FN + col]));
  }
  smax[threadIdx.x] = m;
  __syncthreads();
  if (threadIdx.x < 4) {
    float mm = smax[threadIdx.x];
#pragma unroll 8
    for (int g2 = 1; g2 < 64; ++g2) mm = fmaxf(mm, smax[g2 * 4 + threadIdx.x]);
    const float wb = fmaxf(mm, 1e-6f);
    const float ws = 127.f / wb;               // f32 divide, matches jnp w_scale
    sscale[threadIdx.x] = ws;
    invcs[blockIdx.x * 4 + threadIdx.x] =
        (float)(1.0 / ((double)A_SCALE_F * (double)ws));
  }
  __syncthreads();
  const float ws = sscale[c];
  uint32_t* wq32 = (uint32_t*)(wq + (size_t)col * DK);
#pragma unroll
  for (int d = 0; d < 2; ++d) {                // 8 rows -> 2 packed words
    uint32_t p = 0;
#pragma unroll
    for (int j = 0; j < 4; ++j) {
      float v = kern[(size_t)(g * 8 + d * 4 + j) * FN + col] * ws;
      v = floorf(v + 0.5f);                    // AQT round: floor(v+0.5)
      v = fminf(fmaxf(v, -127.f), 127.f);
      p |= ((uint32_t)((int)v & 255)) << (8 * j);
    }
    wq32[g * 2 + d] = p;
  }
}

// ---------------- fused GEMM: quantize x on the fly, pipelined over 16 tiles ---
// Per tile: issue f32 loads(t+1) [16 VGPR] -> K-loop(t) MFMA -> quantize+ds_write
// (t+1, XOR-swizzled) -> epilogue stores(t) -> lgkmcnt(0)+raw barrier (stores
// float across the barrier; loads float across the K-loop).
__global__ __launch_bounds__(GT, 4)
void aqt_gemm_fused(const float* __restrict__ x,     // [B_ROWS][DK]
                    const int8_t* __restrict__ wq,   // [FN][DK]
                    const float* __restrict__ invcs, // [FN]
                    const float* __restrict__ bias,  // [FN]
                    float* __restrict__ out) {       // [B_ROWS][FN]
  __shared__ __align__(16) uint8_t xq[2][BMS * DK];  // 2 x 16 KB

  const int tid  = threadIdx.x;
  const int lane = tid & 63;
  const int wv   = tid >> 6;       // 0..15
  const int l31  = lane & 31;
  const int l5   = lane >> 5;

  const int c4 = tid & 127;        // float4 col within a row
  const int r0 = tid >> 7;         // 0..7 -> rows r0, r0+8, r0+16, r0+24

  // ---- B fragments into registers, once (256 KB, L2-hot) ----
  const int col = wv * 32 + l31;
  int32x4 Bf[16];
#pragma unroll
  for (int ks = 0; ks < 16; ++ks)
    Bf[ks] = *(const int32x4*)(wq + (size_t)col * DK + ks * 32 + l5 * 16);
  const float inv = invcs[col];
  const float bv  = bias[col];

  const size_t row0 = (size_t)blockIdx.x * (GTILES * BMS);

  // ---- prologue: stage tile 0 into buffer 0 ----
  {
    const float* xg = x + row0 * DK;
    floatx4 v[4];
#pragma unroll
    for (int i = 0; i < 4; ++i)
      v[i] = *(const floatx4*)(xg + (size_t)(i * 8 + r0) * DK + c4 * 4);
#pragma unroll
    for (int i = 0; i < 4; ++i) {
      const int r = i * 8 + r0;
      uint32_t p = 0;
#pragma unroll
      for (int j = 0; j < 4; ++j) {
        float q = floorf(v[i][j] * A_SCALE_F + 0.5f);   // AQT round
        q = fminf(fmaxf(q, -127.f), 127.f);
        p |= ((uint32_t)((int)q & 255)) << (8 * j);
      }
      *(uint32_t*)(&xq[0][r * DK + ((c4 * 4) ^ ((r & 31) << 4))]) = p;
    }
  }
  asm volatile("s_waitcnt lgkmcnt(0)" ::: "memory");
  __builtin_amdgcn_s_barrier();

  for (int t = 0; t < GTILES; ++t) {
    const uint8_t* bufC = &xq[t & 1][0];
    uint8_t* bufN = &xq[(t & 1) ^ 1][0];
    const size_t rowT = row0 + (size_t)t * BMS;
    const bool pf = (t + 1 < GTILES);

    // ---- issue f32 loads for tile t+1 (latency hides under K-loop) ----
    floatx4 v[4];
    if (pf) {
      const float* xg = x + (rowT + BMS) * DK;
#pragma unroll
      for (int i = 0; i < 4; ++i)
        v[i] = *(const floatx4*)(xg + (size_t)(i * 8 + r0) * DK + c4 * 4);
    }

    // ---- K-loop: LDS A + in-register B only ----
    int32x16 acc = (int32x16)(0);
    const uint8_t* aRow = bufC + l31 * DK;
    const int aswz = l31 << 4;
#pragma unroll
    for (int ks = 0; ks < 16; ++ks) {
      int32x4 a = *(const int32x4*)(aRow + ((ks * 32 + l5 * 16) ^ aswz));
      acc = __builtin_amdgcn_mfma_i32_32x32x32_i8(a, Bf[ks], acc, 0, 0, 0);
    }

    // ---- quantize tile t+1 into the other buffer ----
    if (pf) {
#pragma unroll
      for (int i = 0; i < 4; ++i) {
        const int r = i * 8 + r0;
        uint32_t p = 0;
#pragma unroll
        for (int j = 0; j < 4; ++j) {
          float q = floorf(v[i][j] * A_SCALE_F + 0.5f);   // AQT round
          q = fminf(fmaxf(q, -127.f), 127.f);
          p |= ((uint32_t)((int)q & 255)) << (8 * j);
        }
        *(uint32_t*)(&bufN[r * DK + ((c4 * 4) ^ ((r & 31) << 4))]) = p;
      }
    }

    // ---- epilogue: 16 full-128B-segment stores (R3-validated C/D layout) ----
#pragma unroll
    for (int r = 0; r < 16; ++r) {
      const int rowl = (r & 3) + 8 * (r >> 2) + 4 * l5;
      out[(rowT + rowl) * FN + col] = (float)acc[r] * inv + bv;
    }

    // ds_writes must be visible; stores keep draining across the barrier.
    asm volatile("s_waitcnt lgkmcnt(0)" ::: "memory");
    __builtin_amdgcn_s_barrier();
  }
}

extern "C" void kernel_launch(void* const* d_in, const int* in_sizes, int n_in,
                              void* d_out, int out_size, void* d_ws, size_t ws_size,
                              hipStream_t stream) {
  const float* x    = (const float*)d_in[0];
  const float* kern = (const float*)d_in[1];
  const float* bias = (const float*)d_in[2];
  // d_in[3] = padding_mask: fixed act bounds + eval mode -> not in the math.

  int8_t* wq    = (int8_t*)d_ws;                            // 256 KB
  float*  invcs = (float*)((char*)d_ws + (size_t)FN * DK);  // 2 KB

  wq_quant_kernel<<<128, 256, 0, stream>>>(kern, wq, invcs);
  aqt_gemm_fused<<<GBLK, GT, 0, stream>>>(x, wq, invcs, bias, (float*)d_out);
}